// Round 25
// baseline (49.286 us; speedup 1.0000x reference)
//
#include <hip/hip_runtime.h>
#include <stdint.h>
#include <float.h>

// Chamfer distance, B=4, N=M=4096, 3D fp32.
// Outputs (flat, float32): [0] loss, [1..16384] idx12 (float), [16385..32768] idx21.
//
// SEMANTIC CONTRACT (validated R14-R24, absmax 0.0 — do not change):
//   d in f64: d = fma(dx,dx, fma(dy,dy, dz*dz)), dx = x - bx (f64-promoted f32)
//   pick = smallest index j with d_j <= fma(TOL_K(dir), a2 + b2_j, dmin)
//     (a2, b2_j in f64 from promoted f32 coords)
//   K12 = 0.6*2^-23, K21 = 0.   dmin = exact f64 min over prefilter survivors.
//   Prefilter (R16-proven 2x margin): survivor iff
//     d32 <= fma(2e-7, a2f+b2f_j, me), me = m*(1+2e-6), m = global f32 min.
//   Split skip (R18-validated): skip iff splitmin > (me + 7e-7*a2f)*(1+4e-6).
//
// R25: timing model fit across R14-R24: dur ≈ max(41us harness per-replay
// 268MB fill, kernel chain). Kernel chain ~48 (select ~30: TWO global candidate
// passes + reloads between serial shuffle chains). Fix: pass 1 register-caches
// candidates {d64, M, j} (4 static slots/lane, no runtime indexing -> no
// scratch); pass 2 is register-only; per-lane overflow (>4) falls back to the
// verbatim memory walk. min32 PPT 8->4 for TLP. All contract formulas verbatim.

constexpr int B_ = 4;
constexpr int N_ = 4096;
constexpr int PTS = 256;
constexpr int PPT = 4;                   // points per thread (min32)
constexpr int TILES = N_ / (PTS * PPT);  // 4
constexpr int JSPLIT = 32;
constexpr int CHUNK = N_ / JSPLIT;       // 128
constexpr double EPS32 = 1.1920928955078125e-7;  // 2^-23
constexpr double TOL_K12 = 0.6 * EPS32;
constexpr double TOL_K21 = 0.0;
constexpr double BETA_ = 1.0;
constexpr double GAMMA_ = 1.0;
constexpr double DELTA_ = 0.0;

// grid: (TILES*B_*2, JSPLIT)
__global__ __launch_bounds__(256) void cd_min32(
        const float* __restrict__ xyz1, const float* __restrict__ xyz2,
        unsigned int* __restrict__ splitmin, float4* __restrict__ b4) {
    const int tile  = blockIdx.x % TILES;
    const int b     = (blockIdx.x / TILES) % B_;
    const int dir   = blockIdx.x / (TILES * B_);
    const int split = blockIdx.y;
    const float* A  = dir ? xyz2 : xyz1;
    const float* Bc = dir ? xyz1 : xyz2;
    const size_t ob = (size_t)dir * B_ + b;

    __shared__ float4 s[CHUNK];          // 2 KiB
    const float* bbase = Bc + ((size_t)b * N_ + (size_t)split * CHUNK) * 3;
    if (threadIdx.x < CHUNK) {
        int j = threadIdx.x;
        float bx = bbase[3 * j], by = bbase[3 * j + 1], bz = bbase[3 * j + 2];
        float b2 = bx * bx + by * by + bz * bz;   // prefilter-only (margin ok)
        float4 v = make_float4(bx, by, bz, b2);
        s[j] = v;
        if (tile == 0)                    // one writer per (dir,b,split)
            b4[ob * N_ + (size_t)split * CHUNK + j] = v;
    }
    __syncthreads();

    float px[PPT], py[PPT], pz[PPT], mn[PPT];
    #pragma unroll
    for (int pi = 0; pi < PPT; ++pi) {
        const int p = tile * (PTS * PPT) + pi * PTS + threadIdx.x;
        const float* ap = A + ((size_t)b * N_ + p) * 3;
        px[pi] = ap[0]; py[pi] = ap[1]; pz[pi] = ap[2];
        mn[pi] = FLT_MAX;
    }

    #pragma unroll 4
    for (int j = 0; j < CHUNK; ++j) {
        float4 bv = s[j];
        #pragma unroll
        for (int pi = 0; pi < PPT; ++pi) {
            float dx = px[pi] - bv.x, dy = py[pi] - bv.y, dz = pz[pi] - bv.z;
            mn[pi] = fminf(mn[pi],
                           __fmaf_rn(dx, dx, __fmaf_rn(dy, dy, dz * dz)));
        }
    }

    const size_t sm = (ob * JSPLIT + split) * N_;
    #pragma unroll
    for (int pi = 0; pi < PPT; ++pi) {
        const int p = tile * (PTS * PPT) + pi * PTS + threadIdx.x;
        splitmin[sm + p] = __float_as_uint(mn[pi]);   // block-owned store
    }
}

// one wave per point; grid: (2*B_*N_)/4 = 8192 blocks of 256 (4 waves/block)
__global__ __launch_bounds__(256) void cd_select(
        const float* __restrict__ xyz1, const float* __restrict__ xyz2,
        const unsigned int* __restrict__ splitmin, const float4* __restrict__ b4,
        double* __restrict__ dminArr, float* __restrict__ out) {
    const int W0   = blockIdx.x * 4;                 // first point id of block
    const int dir  = W0 / (B_ * N_);
    const int b    = (W0 / N_) % B_;
    const int p0   = W0 % N_;
    const float* A  = dir ? xyz2 : xyz1;
    const double tolk = dir ? TOL_K21 : TOL_K12;
    const size_t ob = (size_t)dir * B_ + b;
    const float4* bb4 = b4 + ob * N_;

    __shared__ unsigned int lt[4][32];               // 512 B panel

    if (threadIdx.x < 128) {
        const int s  = threadIdx.x >> 2;
        const int pi = threadIdx.x & 3;
        lt[pi][s] = splitmin[(ob * JSPLIT + s) * N_ + p0 + pi];
    }
    __syncthreads();

    const int wv   = threadIdx.x >> 6;               // wave -> point p0+wv
    const int lane = threadIdx.x & 63;
    const int p    = p0 + wv;
    const int W    = W0 + wv;

    const float* ap = A + ((size_t)b * N_ + p) * 3;
    const float x = ap[0], y = ap[1], z = ap[2];
    const float a2f = x * x + y * y + z * z;

    // m = min over 32 per-split minima (== global f32 min, bit-identical)
    const int l32 = lane & 31;
    const float sv = __uint_as_float(lt[wv][l32]);
    float m = sv;
    #pragma unroll
    for (int off = 1; off < 32; off <<= 1)
        m = fminf(m, __shfl_xor(m, off));

    const float me = __fmaf_rn(2e-6f, m, m);         // m*(1+2e-6)
    const float skipthr = (me + 7e-7f * a2f) * (1.0f + 4e-6f);
    const unsigned int mask = (unsigned int)__ballot(lane < 32 && sv <= skipthr);

    const double xd = (double)x, yd = (double)y, zd = (double)z;
    const double a2 = xd * xd + yd * yd + zd * zd;

    // pass 1: f64 dmin over prefilter survivors, register-caching candidates
    // (static slots only — runtime-indexed arrays would spill to scratch)
    double dmin = 1.0e300;
    double cd0 = 1.0e300, cd1 = 1.0e300, cd2 = 1.0e300, cd3 = 1.0e300;
    double cM0 = 0.0, cM1 = 0.0, cM2 = 0.0, cM3 = 0.0;
    unsigned int cj0 = 0xFFFFFFFFu, cj1 = 0xFFFFFFFFu,
                 cj2 = 0xFFFFFFFFu, cj3 = 0xFFFFFFFFu;
    int nc = 0;
    bool ovf = false;

    unsigned int mk = mask;
    while (mk) {
        int s = __ffs(mk) - 1; mk &= mk - 1;
        int j0 = s * CHUNK + lane;
        float4 bv0 = bb4[j0];
        float4 bv1 = bb4[j0 + 64];
        #pragma unroll
        for (int k = 0; k < 2; ++k) {
            float4 bv = k ? bv1 : bv0;
            int j = j0 + k * 64;
            float dx = x - bv.x, dy = y - bv.y, dz = z - bv.z;
            float d32 = __fmaf_rn(dx, dx, __fmaf_rn(dy, dy, dz * dz));
            float thr = __fmaf_rn(2e-7f, a2f + bv.w, me);
            if (d32 <= thr) {
                double bxd = (double)bv.x, byd = (double)bv.y, bzd = (double)bv.z;
                double ddx = xd - bxd, ddy = yd - byd, ddz = zd - bzd;
                double d64 = fma(ddx, ddx, fma(ddy, ddy, ddz * ddz));
                double M   = a2 + (bxd * bxd + byd * byd + bzd * bzd);
                dmin = fmin(dmin, d64);
                if      (nc == 0) { cd0 = d64; cM0 = M; cj0 = (unsigned int)j; }
                else if (nc == 1) { cd1 = d64; cM1 = M; cj1 = (unsigned int)j; }
                else if (nc == 2) { cd2 = d64; cM2 = M; cj2 = (unsigned int)j; }
                else if (nc == 3) { cd3 = d64; cM3 = M; cj3 = (unsigned int)j; }
                else ovf = true;
                ++nc;
            }
        }
    }
    #pragma unroll
    for (int off = 1; off < 64; off <<= 1)
        dmin = fmin(dmin, __shfl_xor(dmin, off));

    // pass 2: register-only contract pick (slots init'd so empty slots fail)
    unsigned int pick = 0xFFFFFFFFu;
    if (cd0 <= fma(tolk, cM0, dmin)) pick = (cj0 < pick) ? cj0 : pick;
    if (cd1 <= fma(tolk, cM1, dmin)) pick = (cj1 < pick) ? cj1 : pick;
    if (cd2 <= fma(tolk, cM2, dmin)) pick = (cj2 < pick) ? cj2 : pick;
    if (cd3 <= fma(tolk, cM3, dmin)) pick = (cj3 < pick) ? cj3 : pick;

    if (ovf) {                                       // rare: verbatim memory walk
        unsigned int mk2 = mask;
        while (mk2) {
            int s = __ffs(mk2) - 1; mk2 &= mk2 - 1;
            int j0 = s * CHUNK + lane;
            float4 bv0 = bb4[j0];
            float4 bv1 = bb4[j0 + 64];
            #pragma unroll
            for (int k = 0; k < 2; ++k) {
                float4 bv = k ? bv1 : bv0;
                int j = j0 + k * 64;
                float dx = x - bv.x, dy = y - bv.y, dz = z - bv.z;
                float d32 = __fmaf_rn(dx, dx, __fmaf_rn(dy, dy, dz * dz));
                float thr = __fmaf_rn(2e-7f, a2f + bv.w, me);
                if (d32 <= thr) {
                    double bxd = (double)bv.x, byd = (double)bv.y,
                           bzd = (double)bv.z;
                    double ddx = xd - bxd, ddy = yd - byd, ddz = zd - bzd;
                    double d64 = fma(ddx, ddx, fma(ddy, ddy, ddz * ddz));
                    double M   = a2 + (bxd * bxd + byd * byd + bzd * bzd);
                    if (d64 <= fma(tolk, M, dmin))
                        pick = (pick < (unsigned int)j) ? pick : (unsigned int)j;
                }
            }
        }
    }
    #pragma unroll
    for (int off = 1; off < 64; off <<= 1) {
        unsigned int o2 = (unsigned int)__shfl_xor((int)pick, off);
        pick = (o2 < pick) ? o2 : pick;
    }

    if (lane == 0) {
        dminArr[W] = dmin;
        const size_t obase = (dir == 0) ? (1 + (size_t)b * N_)
                                        : (1 + (size_t)B_ * N_ + (size_t)b * N_);
        out[obase + p] = (float)pick;
    }
}

__global__ __launch_bounds__(256) void cd_finalize(
        const double* __restrict__ dminArr, float* __restrict__ out,
        double* __restrict__ loss_part) {
    const int b = blockIdx.x;
    const int t = threadIdx.x;

    double sum12 = 0.0, max12 = -1.0e300, sum21 = 0.0;
    for (int n = t; n < N_; n += 256) {
        double d12 = dminArr[(size_t)b * N_ + n];
        double d21 = dminArr[((size_t)B_ + b) * N_ + n];
        sum12 += d12;
        max12 = fmax(max12, d12);
        sum21 += d21;
    }
    __shared__ double s1[256], s2[256], s3[256];
    s1[t] = sum12; s2[t] = max12; s3[t] = sum21;
    __syncthreads();
    for (int off = 128; off > 0; off >>= 1) {
        if (t < off) {
            s1[t] += s1[t + off];
            s2[t]  = fmax(s2[t], s2[t + off]);
            s3[t] += s3[t + off];
        }
        __syncthreads();
    }
    if (t == 0) {
        loss_part[b] = s1[0] / (double)N_ + BETA_ * s2[0]
                     + (GAMMA_ + DELTA_ * (double)N_) * (s3[0] / (double)N_);
    }
}

__global__ void cd_loss(const double* __restrict__ loss_part,
                        float* __restrict__ out) {
    if (blockIdx.x == 0 && threadIdx.x == 0) {
        double s = 0.0;
        for (int b = 0; b < B_; ++b) s += loss_part[b];  // fixed order
        out[0] = (float)(s / (double)B_);
    }
}

extern "C" void kernel_launch(void* const* d_in, const int* in_sizes, int n_in,
                              void* d_out, int out_size, void* d_ws, size_t ws_size,
                              hipStream_t stream) {
    const float* xyz1 = (const float*)d_in[0];
    const float* xyz2 = (const float*)d_in[1];
    float* out = (float*)d_out;

    const size_t NP = (size_t)2 * B_ * N_;       // 32768 points
    double* dminArr   = (double*)d_ws;           // NP doubles
    double* loss_part = dminArr + NP;            // B_ doubles
    unsigned int* splitmin = (unsigned int*)(loss_part + B_);  // NP*JSPLIT (4 MiB)
    float4* b4 = (float4*)(splitmin + NP * JSPLIT);            // 512 KiB

    dim3 grid(TILES * B_ * 2, JSPLIT);
    cd_min32<<<grid, PTS, 0, stream>>>(xyz1, xyz2, splitmin, b4);

    cd_select<<<(int)(NP / 4), 256, 0, stream>>>(xyz1, xyz2, splitmin, b4,
                                                 dminArr, out);

    cd_finalize<<<B_, 256, 0, stream>>>(dminArr, out, loss_part);
    cd_loss<<<1, 64, 0, stream>>>(loss_part, out);
}